// Round 1
// baseline (5433.627 us; speedup 1.0000x reference)
//
#include <hip/hip_runtime.h>
#include <math.h>

#define CIN 64
#define CE  64
#define HH  256
#define WW  256
#define OHW 128

// ---------------- gate: global average pool ----------------
__global__ __launch_bounds__(256)
void pool_kernel(const float* __restrict__ x, float* __restrict__ pooled) {
    int bc = blockIdx.x;  // 0..B*CIN-1
    const float4* p = reinterpret_cast<const float4*>(x + (size_t)bc * (HH * WW));
    float s = 0.f;
    for (int i = threadIdx.x; i < (HH * WW) / 4; i += 256) {
        float4 v = p[i];
        s += (v.x + v.y) + (v.z + v.w);
    }
#pragma unroll
    for (int m = 32; m >= 1; m >>= 1) s += __shfl_xor(s, m, 64);
    __shared__ float red[4];
    int lane = threadIdx.x & 63, wv = threadIdx.x >> 6;
    if (lane == 0) red[wv] = s;
    __syncthreads();
    if (threadIdx.x == 0) {
        float t = (red[0] + red[1]) + (red[2] + red[3]);
        pooled[bc] = t * (1.0f / (HH * WW));
    }
}

// ---------------- gate: linear -> softmax -> top2 ----------------
__global__ __launch_bounds__(64)
void gate_kernel(const float* __restrict__ pooled, const float* __restrict__ gw,
                 const float* __restrict__ gb, int* __restrict__ sel_idx,
                 float* __restrict__ sel_w) {
    int b = blockIdx.x;
    int c = threadIdx.x;  // 0..63 == CIN
    float p = pooled[b * CIN + c];
    float l[4];
#pragma unroll
    for (int e = 0; e < 4; ++e) l[e] = p * gw[e * CIN + c];
#pragma unroll
    for (int m = 32; m >= 1; m >>= 1) {
#pragma unroll
        for (int e = 0; e < 4; ++e) l[e] += __shfl_xor(l[e], m, 64);
    }
    if (c == 0) {
        float g[4], s = 0.f;
#pragma unroll
        for (int e = 0; e < 4; ++e) l[e] += gb[e];
        float mx = fmaxf(fmaxf(l[0], l[1]), fmaxf(l[2], l[3]));
#pragma unroll
        for (int e = 0; e < 4; ++e) { g[e] = expf(l[e] - mx); s += g[e]; }
#pragma unroll
        for (int e = 0; e < 4; ++e) g[e] /= s;
        int i1 = 0;
        for (int e = 1; e < 4; ++e) if (g[e] > g[i1]) i1 = e;   // first index wins ties
        int i2 = -1;
        for (int e = 0; e < 4; ++e) {
            if (e == i1) continue;
            if (i2 < 0 || g[e] > g[i2]) i2 = e;
        }
        float den = g[i1] + g[i2] + 1e-8f;
        sel_idx[b * 2 + 0] = i1;
        sel_idx[b * 2 + 1] = i2;
        sel_w[b * 2 + 0] = g[i1] / den;
        sel_w[b * 2 + 1] = g[i2] / den;
    }
}

// ---------------- expert conv body (compile-time K, D) ----------------
template <int K, int D>
__device__ __forceinline__ void conv_body(const float* __restrict__ xb,
                                          const float* __restrict__ we,
                                          float* __restrict__ xt, float* __restrict__ wt,
                                          int ih0, int iw0, float* acc, int lane, int wv) {
    constexpr int K2 = K * K;
    constexpr int TS = 31 + (K - 1) * D;  // input tile span for 16 outputs @ stride 2
    int t = wv * 64 + lane;
    int r = lane >> 2, cq = lane & 3;
    int co_l = t >> 2, kko = t & 3;
    const float* wbase = we + (size_t)co_l * (CIN * K2);
#pragma unroll 1
    for (int ci = 0; ci < CIN; ++ci) {
        __syncthreads();
        const float* xc = xb + (size_t)ci * (HH * WW);
        // stage input tile: wave handles rows wv, wv+4, ... ; lane = column
#pragma unroll 1
        for (int row = wv; row < TS; row += 4) {
            if (lane < TS) {
                int ih = ih0 + row;
                int iw = iw0 + lane;
                float v = 0.f;
                if ((unsigned)ih < HH && (unsigned)iw < WW) v = xc[ih * WW + iw];
                xt[row * 65 + lane] = v;
            }
        }
        // stage weights as [k2][64co]
        const float* wc = wbase + ci * K2;
#pragma unroll 1
        for (int kk = kko; kk < K2; kk += 4) wt[kk * 64 + co_l] = wc[kk];
        __syncthreads();
#pragma unroll 1
        for (int kh = 0; kh < K; ++kh) {
            int xrb = (2 * r + kh * D) * 65;
#pragma unroll
            for (int kw = 0; kw < K; ++kw) {
                int xcb = cq * 8 + kw * D;
                float xv0 = xt[xrb + xcb + 0];
                float xv1 = xt[xrb + xcb + 2];
                float xv2 = xt[xrb + xcb + 4];
                float xv3 = xt[xrb + xcb + 6];
                const float4* wp =
                    reinterpret_cast<const float4*>(&wt[(kh * K + kw) * 64 + wv * 16]);
#pragma unroll
                for (int q = 0; q < 4; ++q) {
                    float4 w4 = wp[q];
                    float wf[4] = {w4.x, w4.y, w4.z, w4.w};
#pragma unroll
                    for (int cc = 0; cc < 4; ++cc) {
                        float* ap = acc + (q * 4 + cc) * 4;
                        ap[0] += wf[cc] * xv0;
                        ap[1] += wf[cc] * xv1;
                        ap[2] += wf[cc] * xv2;
                        ap[3] += wf[cc] * xv3;
                    }
                }
            }
        }
    }
}

// ---------------- conv + BN + GELU + gate-weight ----------------
__global__ __launch_bounds__(256, 2)
void conv_kernel(const float* __restrict__ x, const float* __restrict__ w0_,
                 const float* __restrict__ w1_, const float* __restrict__ w2_,
                 const float* __restrict__ w3_, const float* __restrict__ b0_,
                 const float* __restrict__ b1_, const float* __restrict__ b2_,
                 const float* __restrict__ b3_, const float* __restrict__ bns,
                 const float* __restrict__ bnb, const float* __restrict__ bnm,
                 const float* __restrict__ bnv, const int* __restrict__ sel_idx,
                 const float* __restrict__ sel_w, float* __restrict__ out) {
    __shared__ float xt[63 * 65];
    __shared__ float wt[81 * 64];
    int bs = blockIdx.x;               // b*2 + slot  (fastest dim -> expert mix across CUs)
    int b = bs >> 1, slot = bs & 1;
    int e = sel_idx[bs];
    float gwt = sel_w[bs];
    int tile = blockIdx.y;
    int oh0 = (tile >> 3) * 16, ow0 = (tile & 7) * 16;
    const int KS_[4] = {3, 5, 7, 9}, DS_[4] = {1, 2, 3, 4};
    int k = KS_[e], d = DS_[e];
    int pad = (d * (k - 1)) >> 1;
    int ih0 = oh0 * 2 - pad, iw0 = ow0 * 2 - pad;
    const float* xb = x + (size_t)b * CIN * HH * WW;
    const float* we = (e == 0) ? w0_ : (e == 1) ? w1_ : (e == 2) ? w2_ : w3_;
    const float* be = (e == 0) ? b0_ : (e == 1) ? b1_ : (e == 2) ? b2_ : b3_;
    int t = threadIdx.x, lane = t & 63, wv = t >> 6;
    float acc[64];
#pragma unroll
    for (int i = 0; i < 64; ++i) acc[i] = 0.f;
    switch (e) {
        case 0: conv_body<3, 1>(xb, we, xt, wt, ih0, iw0, acc, lane, wv); break;
        case 1: conv_body<5, 2>(xb, we, xt, wt, ih0, iw0, acc, lane, wv); break;
        case 2: conv_body<7, 3>(xb, we, xt, wt, ih0, iw0, acc, lane, wv); break;
        default: conv_body<9, 4>(xb, we, xt, wt, ih0, iw0, acc, lane, wv); break;
    }
    // epilogue: bias -> BN -> exact GELU -> gate weight
    int r = lane >> 2, cq = lane & 3;
    size_t obase = ((size_t)(b * 128 + slot * 64) * OHW + (oh0 + r)) * OHW + ow0 + cq * 4;
#pragma unroll 1
    for (int q = 0; q < 4; ++q) {
#pragma unroll
        for (int cc = 0; cc < 4; ++cc) {
            int co = wv * 16 + q * 4 + cc;
            float bias = be[co];
            float sc = bns[e * CE + co], bi = bnb[e * CE + co];
            float mn = bnm[e * CE + co], vr = bnv[e * CE + co];
            float inv = sc / sqrtf(vr + 1e-5f);
            float beta = bi - mn * inv;
            float* ap = &acc[(q * 4 + cc) * 4];
            float4 o;
            float ys[4];
#pragma unroll
            for (int j = 0; j < 4; ++j) {
                float y = (ap[j] + bias) * inv + beta;
                float g = 0.5f * y * (1.0f + erff(y * 0.70710678118654752f));
                ys[j] = g * gwt;
            }
            o.x = ys[0]; o.y = ys[1]; o.z = ys[2]; o.w = ys[3];
            *reinterpret_cast<float4*>(&out[obase + (size_t)co * (OHW * OHW)]) = o;
        }
    }
}

extern "C" void kernel_launch(void* const* d_in, const int* in_sizes, int n_in,
                              void* d_out, int out_size, void* d_ws, size_t ws_size,
                              hipStream_t stream) {
    const float* x   = (const float*)d_in[0];
    const float* w0  = (const float*)d_in[1];
    const float* b0  = (const float*)d_in[2];
    const float* w1  = (const float*)d_in[3];
    const float* b1  = (const float*)d_in[4];
    const float* w2  = (const float*)d_in[5];
    const float* b2  = (const float*)d_in[6];
    const float* w3  = (const float*)d_in[7];
    const float* b3  = (const float*)d_in[8];
    const float* bns = (const float*)d_in[9];
    const float* bnb = (const float*)d_in[10];
    const float* bnm = (const float*)d_in[11];
    const float* bnv = (const float*)d_in[12];
    const float* gw  = (const float*)d_in[13];
    const float* gb  = (const float*)d_in[14];
    float* out = (float*)d_out;

    float* pooled = (float*)d_ws;              // 1024 floats
    int* sel_idx  = ((int*)d_ws) + 1024;       // 32 ints
    float* sel_w  = ((float*)d_ws) + 1056;     // 32 floats

    pool_kernel<<<dim3(16 * CIN), 256, 0, stream>>>(x, pooled);
    gate_kernel<<<dim3(16), 64, 0, stream>>>(pooled, gw, gb, sel_idx, sel_w);
    conv_kernel<<<dim3(32, 64), 256, 0, stream>>>(x, w0, w1, w2, w3, b0, b1, b2, b3,
                                                  bns, bnb, bnm, bnv, sel_idx, sel_w, out);
}